// Round 2
// 240.302 us; speedup vs baseline: 1.0138x; 1.0138x over previous
//
#include <hip/hip_runtime.h>
#include <math.h>

// Problem: B=8, C=64, T=16, H=64, W=64, text_dim=768
// out[b,c,:,h,w] = D^T diag(w[b,c,:]) D @ r[b,c,:,h,w]
// w[b, c*16+k] = sigmoid(E_txt[b] . Wf[c*16+k] + bf[c*16+k])

#define HW4 1024         // H*W/4 (float4 units)

// native vector type: __builtin_nontemporal_* accepts these (not HIP float4)
typedef float f4 __attribute__((ext_vector_type(4)));

// ---------------- Kernel A: gate GEMM + sigmoid -> w[8192] ----------------
// UNCHANGED (bitwise-identical w values).
__global__ __launch_bounds__(256) void gate_kernel(
    const float* __restrict__ E,    // (8, 768)
    const float* __restrict__ Wf,   // (1024, 768)
    const float* __restrict__ bf,   // (1024,)
    float* __restrict__ wout)       // (8192,) indexed [bc*16+k]
{
    const int wave = threadIdx.x >> 6;
    const int lane = threadIdx.x & 63;
    const int ct   = blockIdx.x * 4 + wave;

    const float4* W4 = (const float4*)(Wf) + ct * 192;
    const float4* E4 = (const float4*)E;

    float acc[8];
#pragma unroll
    for (int b = 0; b < 8; ++b) acc[b] = 0.f;

#pragma unroll
    for (int j = 0; j < 3; ++j) {
        float4 a = W4[j * 64 + lane];
#pragma unroll
        for (int b = 0; b < 8; ++b) {
            float4 e = E4[b * 192 + j * 64 + lane];
            acc[b] = fmaf(a.x, e.x, acc[b]);
            acc[b] = fmaf(a.y, e.y, acc[b]);
            acc[b] = fmaf(a.z, e.z, acc[b]);
            acc[b] = fmaf(a.w, e.w, acc[b]);
        }
    }
#pragma unroll
    for (int off = 32; off >= 1; off >>= 1) {
#pragma unroll
        for (int b = 0; b < 8; ++b)
            acc[b] += __shfl_xor(acc[b], off, 64);
    }
    const float bias = bf[ct];
#pragma unroll
    for (int b = 0; b < 8; ++b) {
        if (lane == b) {
            float s = acc[b] + bias;
            wout[b * 1024 + ct] = 1.0f / (1.0f + expf(-s));
        }
    }
}

// ------- Kernel B: fused M-build + streaming transform y = M @ x -------
// 2048 blocks x 256 threads (4 waves). bc = blk>>2; wave w handles
// chunk = (blk&3)*4 + w  (64 f4 columns each; 16 chunks cover HW).
// Each block redundantly builds its 16x16 M = D^T diag(w) D in LDS
// (identical arithmetic to the old buildM_kernel; stored k-major so the
// inner loop reads uniform ds_read_b128). x-prefetch issues BEFORE the
// M-build barrier so HBM latency hides under the build.
// 4-deep x ring keeps data VGPRs at 64(y)+16(xb) -> 4 waves/SIMD.
__global__ __launch_bounds__(256, 4) void mod_kernel(
    const float* __restrict__ r,     // (512, 16, 4096)
    const float* __restrict__ wbuf,  // (8192,) [bc*16+k]
    float* __restrict__ out)
{
    __shared__ float Dl[16][16];
    __shared__ float wv[16];
    __shared__ __align__(16) float Ms[256];   // Ms[k*16+t] = M[t][k]

    const int tid   = threadIdx.x;
    const int wave  = tid >> 6;
    const int lane  = tid & 63;
    const int bc    = blockIdx.x >> 2;
    const int chunk = (blockIdx.x & 3) * 4 + wave;

    const size_t base = (size_t)bc * (16 * 4096);
    const f4* rp = (const f4*)(r + base);
    f4*       op = (f4*)(out + base);
    const int col = chunk * 64 + lane;

    // ---- issue the first 4 x-loads early (latency hides under M build) ----
    f4 xb[4];
#pragma unroll
    for (int k = 0; k < 4; ++k)
        xb[k] = __builtin_nontemporal_load(&rp[k * HW4 + col]);

    // ---- build M (bitwise-identical to the old buildM_kernel) ----
    {
        int k = tid >> 4, n = tid & 15;
        float v = (k == 0) ? 0.25f
                           : cospif((n + 0.5f) * (float)k * (1.0f / 16.0f)) * 0.35355339059327373f;
        Dl[k][n] = v;
        if (tid < 16) wv[tid] = wbuf[bc * 16 + tid];
    }
    __syncthreads();
    {
        int i = tid >> 4, j = tid & 15;
        float s = 0.f;
#pragma unroll
        for (int k = 0; k < 16; ++k)
            s = fmaf(Dl[k][i] * wv[k], Dl[k][j], s);
        Ms[j * 16 + i] = s;   // transposed store: Ms[k*16+t] == M[t][k]
    }
    __syncthreads();

    // ---- streaming transform, k-major (same accumulation order as before) ----
    f4 y[16];
#pragma unroll
    for (int t = 0; t < 16; ++t)
        y[t] = (f4){0.f, 0.f, 0.f, 0.f};

#pragma unroll
    for (int k = 0; k < 16; ++k) {
        f4 xk = xb[k & 3];
        if (k + 4 < 16)
            xb[k & 3] = __builtin_nontemporal_load(&rp[(k + 4) * HW4 + col]);
        const f4* Mk = (const f4*)(Ms + k * 16);
#pragma unroll
        for (int t4 = 0; t4 < 4; ++t4) {
            f4 m = Mk[t4];   // M[4t4+0..3][k], uniform ds_read_b128
            y[4 * t4 + 0].x = fmaf(m.x, xk.x, y[4 * t4 + 0].x);
            y[4 * t4 + 0].y = fmaf(m.x, xk.y, y[4 * t4 + 0].y);
            y[4 * t4 + 0].z = fmaf(m.x, xk.z, y[4 * t4 + 0].z);
            y[4 * t4 + 0].w = fmaf(m.x, xk.w, y[4 * t4 + 0].w);
            y[4 * t4 + 1].x = fmaf(m.y, xk.x, y[4 * t4 + 1].x);
            y[4 * t4 + 1].y = fmaf(m.y, xk.y, y[4 * t4 + 1].y);
            y[4 * t4 + 1].z = fmaf(m.y, xk.z, y[4 * t4 + 1].z);
            y[4 * t4 + 1].w = fmaf(m.y, xk.w, y[4 * t4 + 1].w);
            y[4 * t4 + 2].x = fmaf(m.z, xk.x, y[4 * t4 + 2].x);
            y[4 * t4 + 2].y = fmaf(m.z, xk.y, y[4 * t4 + 2].y);
            y[4 * t4 + 2].z = fmaf(m.z, xk.z, y[4 * t4 + 2].z);
            y[4 * t4 + 2].w = fmaf(m.z, xk.w, y[4 * t4 + 2].w);
            y[4 * t4 + 3].x = fmaf(m.w, xk.x, y[4 * t4 + 3].x);
            y[4 * t4 + 3].y = fmaf(m.w, xk.y, y[4 * t4 + 3].y);
            y[4 * t4 + 3].z = fmaf(m.w, xk.z, y[4 * t4 + 3].z);
            y[4 * t4 + 3].w = fmaf(m.w, xk.w, y[4 * t4 + 3].w);
        }
    }

#pragma unroll
    for (int t = 0; t < 16; ++t)
        __builtin_nontemporal_store(y[t], &op[t * HW4 + col]);
}

extern "C" void kernel_launch(void* const* d_in, const int* in_sizes, int n_in,
                              void* d_out, int out_size, void* d_ws, size_t ws_size,
                              hipStream_t stream) {
    const float* r  = (const float*)d_in[0];   // 33554432
    const float* E  = (const float*)d_in[1];   // 6144
    const float* Wf = (const float*)d_in[2];   // 786432
    const float* bf = (const float*)d_in[3];   // 1024
    float* out = (float*)d_out;
    float* w   = (float*)d_ws;                  // 8192 floats

    gate_kernel<<<256, 256, 0, stream>>>(E, Wf, bf, w);
    mod_kernel <<<2048, 256, 0, stream>>>(r, w, out);
}